// Round 5
// baseline (34229.642 us; speedup 1.0000x reference)
//
#include <hip/hip_runtime.h>
#include <hip/hip_fp16.h>
#include <stdint.h>

#define SEQ_LEN 16384
#define H       512
#define NWG     32      // WG k owns h[16k..16k+16)
#define HK      16
#define T       512
#define NR      48      // rows per matrix per WG (3 gates x 16)
#define WPITCH  257     // uint32 pitch per weight row (256 data + 1 pad)

typedef unsigned long long u64;

#define LD_A(p)   __hip_atomic_load((p),      __ATOMIC_RELAXED, __HIP_MEMORY_SCOPE_AGENT)
#define ST_A(p,v) __hip_atomic_store((p),(v), __ATOMIC_RELAXED, __HIP_MEMORY_SCOPE_AGENT)

// exchange word: [f16 value (hi 16) | step tag (lo 16)]
__global__ void gru_init(uint32_t* __restrict__ tag32) {
    int i = blockIdx.x * blockDim.x + threadIdx.x;
    if (i < H)            ST_A(&tag32[i], 0u);        // h0 = 0, tag 0
    else if (i < 2 * H)   ST_A(&tag32[i], 0xFFFFu);   // invalid tag
}

__launch_bounds__(T, 2)
__global__ void gru_main(const float* __restrict__ x,
                         const float* __restrict__ Wih,
                         const float* __restrict__ Whh,
                         const float* __restrict__ bih,
                         const float* __restrict__ bhh,
                         float* __restrict__ out,
                         uint32_t* __restrict__ tag32)
{
    const int wg  = blockIdx.x;
    const int tid = threadIdx.x;
    const int j0  = wg * HK;

    __shared__ uint32_t w_lds[2 * NR * WPITCH];  // rows 0..47 W_ih, 48..95 W_hh (f16 pairs)
    __shared__ float    x_lds[2][H];
    __shared__ float    h_lds[2][H];
    __shared__ float    sums_g[2][NR];
    __shared__ float    sums_h[2][NR];
    __shared__ float    bsum_g[NR];
    __shared__ float    bsum_h[NR];

    __half* wh = (__half*)w_lds;                 // half pitch = 2*WPITCH

    // ---- prologue: stage weights f32 -> f16 LDS (one row per iter, coalesced) ----
    for (int idx = tid; idx < 2 * NR * H; idx += T) {
        int r  = idx >> 9;                       // 0..95
        int k  = idx & (H - 1);
        int rr = (r < NR) ? r : r - NR;          // 0..47
        int g  = rr >> 4;
        int jj = rr & 15;
        int grow = g * H + j0 + jj;
        float w = (r < NR) ? Wih[(size_t)grow * H + k] : Whh[(size_t)grow * H + k];
        wh[r * (2 * WPITCH) + k] = __float2half(w);
    }
    if (tid < NR) {
        int g  = tid >> 4;
        int jj = tid & 15;
        int grow = g * H + j0 + jj;
        bsum_g[tid] = (g == 2) ? bih[grow] : (bih[grow] + bhh[grow]);
        bsum_h[tid] = (g == 2) ? bhh[grow] : 0.0f;
    }
    if (tid < 128)                               // prefill x_0 into x_lds[0]
        ((float4*)x_lds[0])[tid] = ((const float4*)x)[tid];
    __syncthreads();

    // dot-thread mapping (waves 2..7): row 0..47, chunk 0..7
    const int idxd = tid - 128;
    const int row  = idxd >> 3;                  // 0..47
    const int c8   = idxd & 7;                   // == tid&7 == lane&7

    // ---- W_hh into registers, pre-staggered so loop indices are static ----
    uint32_t wreg[32];
    if (tid >= 128) {
        const uint32_t* wr = w_lds + (NR + row) * WPITCH + c8 * 32;
        #pragma unroll
        for (int i = 0; i < 32; ++i) wreg[i] = wr[(i + 4 * c8) & 31];
    }
    __syncthreads();

    float hprev = 0.0f;                          // own h (wave-2 lanes 0..15)

    for (int t = 0; t < SEQ_LEN; ++t) {
        const int par = t & 1, nxt = par ^ 1;

        if (tid < 128) {
            // ---- issue x_{t+1} prefetch ----
            int tn = (t + 1 < SEQ_LEN) ? (t + 1) : 0;
            float4 xp = ((const float4*)(x + (size_t)tn * H))[tid];

            // ---- depth-3 pipelined spin on 2 u64 (4 h-words) ----
            const uint32_t need = (uint32_t)t & 0xFFFFu;
            const u64 want = (u64)need * 0x0000000100000001ull;
            const u64 M    = 0x0000FFFF0000FFFFull;
            u64* base = (u64*)(tag32 + (size_t)par * H) + 2 * tid;
            u64 va, vb;
            u64 a0 = LD_A(base), b0 = LD_A(base + 1);
            u64 a1 = LD_A(base), b1 = LD_A(base + 1);
            u64 a2 = LD_A(base), b2 = LD_A(base + 1);
            for (;;) {
                if (((a0 & M) == want) & ((b0 & M) == want)) { va = a0; vb = b0; break; }
                a0 = LD_A(base); b0 = LD_A(base + 1);
                __builtin_amdgcn_s_sleep(4);
                if (((a1 & M) == want) & ((b1 & M) == want)) { va = a1; vb = b1; break; }
                a1 = LD_A(base); b1 = LD_A(base + 1);
                __builtin_amdgcn_s_sleep(4);
                if (((a2 & M) == want) & ((b2 & M) == want)) { va = a2; vb = b2; break; }
                a2 = LD_A(base); b2 = LD_A(base + 1);
                __builtin_amdgcn_s_sleep(4);
            }
            int e = 4 * tid;
            h_lds[par][e]     = __half2float(__ushort_as_half((unsigned short)(va >> 16)));
            h_lds[par][e + 1] = __half2float(__ushort_as_half((unsigned short)(va >> 48)));
            h_lds[par][e + 2] = __half2float(__ushort_as_half((unsigned short)(vb >> 16)));
            h_lds[par][e + 3] = __half2float(__ushort_as_half((unsigned short)(vb >> 48)));

            __syncthreads();   // A: h_lds[par] + sums_g[par] ready
            ((float4*)x_lds[nxt])[tid] = xp;     // commit x_{t+1}
            __syncthreads();   // B: sums_h[par] + x_lds[nxt] ready
            // pollers immediately proceed to next step's spin
        } else {
            // ---- gi dots over x_lds[par] (weights from LDS) ----
            {
                const uint32_t* gw = w_lds + row * WPITCH + c8 * 32;
                const float2*   B  = (const float2*)(x_lds[par] + c8 * 64);
                float acc = 0.0f;
                #pragma unroll
                for (int i = 0; i < 32; ++i) {
                    int s = (i + 4 * c8) & 31;
                    uint32_t wp = gw[s];
                    float2 wf = __half22float2(*(__half2*)&wp);
                    float2 b  = B[s];
                    acc = fmaf(wf.x, b.x, fmaf(wf.y, b.y, acc));
                }
                acc += __shfl_xor(acc, 1);
                acc += __shfl_xor(acc, 2);
                acc += __shfl_xor(acc, 4);
                if (c8 == 0) sums_g[par][row] = acc + bsum_g[row];
            }
            __syncthreads();   // A

            // ---- hh dots over h_lds[par] (weights from registers) ----
            {
                const float2* B = (const float2*)(h_lds[par] + c8 * 64);
                float acc = 0.0f;
                #pragma unroll
                for (int i = 0; i < 32; ++i) {
                    int s = (i + 4 * c8) & 31;
                    uint32_t wp = wreg[i];
                    float2 wf = __half22float2(*(__half2*)&wp);
                    float2 b  = B[s];
                    acc = fmaf(wf.x, b.x, fmaf(wf.y, b.y, acc));
                }
                acc += __shfl_xor(acc, 1);
                acc += __shfl_xor(acc, 2);
                acc += __shfl_xor(acc, 4);
                if (c8 == 0) sums_h[par][row] = acc + bsum_h[row];
            }
            __syncthreads();   // B

            // ---- gates + publish: wave 2 only (lanes 0..15 compute, 0..7 store u64) ----
            if (tid < 192) {
                int j = tid & 63;                // lane in wave 2
                uint32_t pk = 0;
                float hnew = 0.0f;
                if (j < 16) {
                    float sg0 = sums_g[par][j],      sg1 = sums_g[par][16 + j], sg2 = sums_g[par][32 + j];
                    float sh0 = sums_h[par][j],      sh1 = sums_h[par][16 + j], sh2 = sums_h[par][32 + j];
                    float r_ = 1.0f / (1.0f + __expf(-(sg0 + sh0)));
                    float z_ = 1.0f / (1.0f + __expf(-(sg1 + sh1)));
                    float a  = sg2 + r_ * sh2;
                    a = fminf(12.0f, fmaxf(-12.0f, a));
                    float e2 = __expf(2.0f * a);
                    float n_ = (e2 - 1.0f) / (e2 + 1.0f);
                    hnew = (1.0f - z_) * n_ + z_ * hprev;
                    hprev = hnew;
                    pk = ((uint32_t)__half_as_ushort(__float2half(hnew)) << 16)
                       | ((uint32_t)(t + 1) & 0xFFFFu);
                }
                uint32_t lo = __shfl(pk, 2 * (j & 31));
                uint32_t hi = __shfl(pk, 2 * (j & 31) + 1);
                if (j < 8) {
                    u64* pb = (u64*)(tag32 + (size_t)nxt * H) + wg * 8 + j;
                    ST_A(pb, ((u64)hi << 32) | (u64)lo);
                }
                if (j < 16) out[(size_t)t * H + j0 + j] = hnew;
            }
            // wave 2 proceeds to next step's gi (its lateness absorbed at barrier A)
        }
    }
}

extern "C" void kernel_launch(void* const* d_in, const int* in_sizes, int n_in,
                              void* d_out, int out_size, void* d_ws, size_t ws_size,
                              hipStream_t stream) {
    const float* x   = (const float*)d_in[0];
    const float* Wih = (const float*)d_in[1];
    const float* Whh = (const float*)d_in[2];
    const float* bih = (const float*)d_in[3];
    const float* bhh = (const float*)d_in[4];
    float* out = (float*)d_out;
    uint32_t* tag32 = (uint32_t*)d_ws;           // 2 * 512 * 4B = 4 KB

    gru_init<<<2, 512, 0, stream>>>(tag32);
    gru_main<<<NWG, T, 0, stream>>>(x, Wih, Whh, bih, bhh, out, tag32);
}

// Round 7
// 33213.535 us; speedup vs baseline: 1.0306x; 1.0306x over previous
//
#include <hip/hip_runtime.h>
#include <hip/hip_fp16.h>
#include <stdint.h>

#define SEQ_LEN 16384
#define H       512
#define NPART   32      // participating WGs (every 8th block -> hopefully one XCD)
#define HK      16      // h elements per participant
#define T       512
#define NR      48      // rows per matrix per WG (3 gates x 16)
#define WPITCH  257     // uint32 pitch per weight row (256 data + 1 pad)
#define FASTK   64      // bounded fast-path sweeps before falling back
#define MAXFAIL 16      // fallback-steps before disabling fast path (per thread)

typedef unsigned long long u64;

#define LD_AG(p)   __hip_atomic_load((p),      __ATOMIC_RELAXED, __HIP_MEMORY_SCOPE_AGENT)
#define ST_AG(p,v) __hip_atomic_store((p),(v), __ATOMIC_RELAXED, __HIP_MEMORY_SCOPE_AGENT)

// ws u32 layout: [0..1023]    fast tags (parity x 512), L2-scope exchange
//               [1024..2047] slow tags (parity x 512), agent-scope exchange
// word: [f16 value (hi 16) | step tag (lo 16)]
__global__ void gru_init(uint32_t* __restrict__ ws) {
    int i = blockIdx.x * blockDim.x + threadIdx.x;
    if (i >= 2048) return;
    int w = i & 1023;
    ST_AG(&ws[i], (w < H) ? 0u : 0xFFFFu);   // par0: h0=0 tag0; par1: invalid
}

// two 8B loads, L1-bypassed (sc0) -> served by the XCD-shared L2
__device__ __forceinline__ void poll2(const u64* p0, const u64* p1, u64& a, u64& b) {
    asm volatile("global_load_dwordx2 %0, %2, off sc0\n\t"
                 "global_load_dwordx2 %1, %3, off sc0\n\t"
                 "s_waitcnt vmcnt(0)"
                 : "=v"(a), "=v"(b) : "v"(p0), "v"(p1) : "memory");
}
__device__ __forceinline__ void pub32(uint32_t* p, uint32_t v) {
    asm volatile("global_store_dword %0, %1, off sc0" :: "v"(p), "v"(v) : "memory");
}

__launch_bounds__(T, 1)
__global__ void gru_main(const float* __restrict__ x,
                         const float* __restrict__ Wih,
                         const float* __restrict__ Whh,
                         const float* __restrict__ bih,
                         const float* __restrict__ bhh,
                         float* __restrict__ out,
                         uint32_t* __restrict__ ws)
{
    if (blockIdx.x & 7) return;              // participants: blocks 0,8,...,248
    const int wg  = blockIdx.x >> 3;         // 0..31
    const int tid = threadIdx.x;
    const int j0  = wg * HK;

    __shared__ uint32_t w_lds[2 * NR * WPITCH];  // rows 0..47 W_ih, 48..95 W_hh (f16 pairs)
    __shared__ float    x_lds[2][H];
    __shared__ float    h_lds[2][H];
    __shared__ float    sums_g[2][NR];
    __shared__ float    bsum_g[NR];
    __shared__ float    bsum_h[NR];

    __half* wh = (__half*)w_lds;

    // ---- stage weights f32 -> f16 LDS ----
    for (int idx = tid; idx < 2 * NR * H; idx += T) {
        int r  = idx >> 9;                       // 0..95
        int k  = idx & (H - 1);
        int rr = (r < NR) ? r : r - NR;
        int g  = rr >> 4;
        int jj = rr & 15;
        int grow = g * H + j0 + jj;
        float w = (r < NR) ? Wih[(size_t)grow * H + k] : Whh[(size_t)grow * H + k];
        wh[r * (2 * WPITCH) + k] = __float2half(w);
    }
    if (tid < NR) {
        int g  = tid >> 4;
        int jj = tid & 15;
        int grow = g * H + j0 + jj;
        bsum_g[tid] = (g == 2) ? bih[grow] : (bih[grow] + bhh[grow]);
        bsum_h[tid] = (g == 2) ? bhh[grow] : 0.0f;
    }
    if (tid < 128)                               // prefill x_0
        ((float4*)x_lds[0])[tid] = ((const float4*)x)[tid];
    __syncthreads();

    // ---- hh weights into registers: rows (lj, 16+lj, 32+lj) x chunk c16, staggered ----
    const int lj  = (tid - 128) >> 4;            // 0..15  (valid for 128<=tid<384)
    const int c16 = (tid - 128) & 15;
    uint32_t wR[16], wZ[16], wN[16];
    if (tid >= 128 && tid < 384) {
        const uint32_t* rR = w_lds + (NR + lj)      * WPITCH + c16 * 16;
        const uint32_t* rZ = w_lds + (NR + 16 + lj) * WPITCH + c16 * 16;
        const uint32_t* rN = w_lds + (NR + 32 + lj) * WPITCH + c16 * 16;
        #pragma unroll
        for (int i = 0; i < 16; ++i) {
            int s = (i + c16) & 15;
            wR[i] = rR[s]; wZ[i] = rZ[s]; wN[i] = rN[s];
        }
    }

    // gi mapping (waves 2..7)
    const int gi_row = (tid - 128) >> 3;         // 0..47
    const int gi_c8  = tid & 7;

    float4 xp;
    if (tid < 128) xp = ((const float4*)(x + H))[tid];   // x_1
    float hprev   = 0.0f;                        // producer lanes' own h (exact f32)
    int   ffail   = 0;                           // poller: fallback-step count
    bool  usefast = true;

    for (int t = 0; t < SEQ_LEN; ++t) {
        const int par = t & 1, nxt = par ^ 1;

        if (tid < 128) {
            // issue x_{t+2} prefetch
            int tq = t + 2; if (tq >= SEQ_LEN) tq = SEQ_LEN - 1;
            float4 xq = ((const float4*)(x + (size_t)tq * H))[tid];

            const uint32_t need = (uint32_t)t & 0xFFFFu;
            const u64 want = (u64)need * 0x0000000100000001ull;
            const u64 M    = 0x0000FFFF0000FFFFull;
            const u64* f = (const u64*)(ws + (size_t)par * H) + 2 * tid;
            const u64* s = (const u64*)(ws + 1024 + (size_t)par * H) + 2 * tid;
            u64 va = 0, vb = 0;
            bool got = false;
            if (usefast) {
                // ---- bounded fast spin on XCD-local L2 ----
                int k = FASTK;
                poll2(f, f + 1, va, vb);
                while ((((va & M) != want) | ((vb & M) != want)) && --k)
                    poll2(f, f + 1, va, vb);
                got = ((va & M) == want) & ((vb & M) == want);
                if (!got && ++ffail >= MAXFAIL) usefast = false;
            }
            if (!got) {
                // ---- proven agent-scope dependent spin (R4 protocol) ----
                do { va = LD_AG(s);     } while ((va & M) != want);
                do { vb = LD_AG(s + 1); } while ((vb & M) != want);
            }
            int e = 4 * tid;
            h_lds[par][e]     = __half2float(__ushort_as_half((unsigned short)(va >> 16)));
            h_lds[par][e + 1] = __half2float(__ushort_as_half((unsigned short)(va >> 48)));
            h_lds[par][e + 2] = __half2float(__ushort_as_half((unsigned short)(vb >> 16)));
            h_lds[par][e + 3] = __half2float(__ushort_as_half((unsigned short)(vb >> 48)));
            __syncthreads();   // A: h_lds[par] + sums_g[par] ready
            ((float4*)x_lds[nxt])[tid] = xp;     // commit x_{t+1}
            xp = xq;
            __syncthreads();   // C: end of step
        } else {
            // ---- gi dots over x_lds[par] (384 threads, weights from LDS) ----
            {
                const uint32_t* gw = w_lds + gi_row * WPITCH + gi_c8 * 32;
                const float2*   B  = (const float2*)(x_lds[par] + gi_c8 * 64);
                float acc = 0.0f;
                #pragma unroll
                for (int i = 0; i < 32; ++i) {
                    int sIdx = (i + 4 * gi_c8) & 31;
                    uint32_t wp = gw[sIdx];
                    float2 wf = __half22float2(*(__half2*)&wp);
                    float2 b  = B[sIdx];
                    acc = fmaf(wf.x, b.x, fmaf(wf.y, b.y, acc));
                }
                acc += __shfl_xor(acc, 1);
                acc += __shfl_xor(acc, 2);
                acc += __shfl_xor(acc, 4);
                if (gi_c8 == 0) sums_g[par][gi_row] = acc + bsum_g[gi_row];
            }
            __syncthreads();   // A

            if (tid < 384) {
                // ---- hh dots: 3 rows/thread from registers over h_lds[par] ----
                const float2* B = (const float2*)(h_lds[par]) + c16 * 16;
                float aR = 0.0f, aZ = 0.0f, aN = 0.0f;
                #pragma unroll
                for (int i = 0; i < 16; ++i) {
                    int sIdx = (i + c16) & 15;
                    float2 b = B[sIdx];
                    float2 fR = __half22float2(*(__half2*)&wR[i]);
                    float2 fZ = __half22float2(*(__half2*)&wZ[i]);
                    float2 fN = __half22float2(*(__half2*)&wN[i]);
                    aR = fmaf(fR.x, b.x, fmaf(fR.y, b.y, aR));
                    aZ = fmaf(fZ.x, b.x, fmaf(fZ.y, b.y, aZ));
                    aN = fmaf(fN.x, b.x, fmaf(fN.y, b.y, aN));
                }
                #pragma unroll
                for (int m = 1; m < 16; m <<= 1) {
                    aR += __shfl_xor(aR, m);
                    aZ += __shfl_xor(aZ, m);
                    aN += __shfl_xor(aN, m);
                }
                if (c16 == 0) {
                    float sh0 = aR + bsum_h[lj];
                    float sh1 = aZ + bsum_h[16 + lj];
                    float sh2 = aN + bsum_h[32 + lj];
                    float sg0 = sums_g[par][lj];
                    float sg1 = sums_g[par][16 + lj];
                    float sg2 = sums_g[par][32 + lj];
                    float r_ = 1.0f / (1.0f + __expf(-(sg0 + sh0)));
                    float z_ = 1.0f / (1.0f + __expf(-(sg1 + sh1)));
                    float a  = sg2 + r_ * sh2;
                    a = fminf(12.0f, fmaxf(-12.0f, a));
                    float e2 = __expf(2.0f * a);
                    float n_ = (e2 - 1.0f) / (e2 + 1.0f);
                    float hnew = (1.0f - z_) * n_ + z_ * hprev;
                    hprev = hnew;
                    uint32_t pk = ((uint32_t)__half_as_ushort(__float2half(hnew)) << 16)
                                | ((uint32_t)(t + 1) & 0xFFFFu);
                    pub32(&ws[(size_t)nxt * H + j0 + lj], pk);            // fast (L2)
                    ST_AG(&ws[1024 + (size_t)nxt * H + j0 + lj], pk);     // slow (agent)
                    out[(size_t)t * H + j0 + lj] = hnew;
                }
            }
            __syncthreads();   // C
        }
    }
}

extern "C" void kernel_launch(void* const* d_in, const int* in_sizes, int n_in,
                              void* d_out, int out_size, void* d_ws, size_t ws_size,
                              hipStream_t stream) {
    const float* x   = (const float*)d_in[0];
    const float* Wih = (const float*)d_in[1];
    const float* Whh = (const float*)d_in[2];
    const float* bih = (const float*)d_in[3];
    const float* bhh = (const float*)d_in[4];
    float* out = (float*)d_out;
    uint32_t* ws = (uint32_t*)d_ws;              // 8 KB exchange

    gru_init<<<4, 512, 0, stream>>>(ws);
    gru_main<<<256, T, 0, stream>>>(x, Wih, Whh, bih, bhh, out, ws);
}